// Round 1
// baseline (334.783 us; speedup 1.0000x reference)
//
#include <hip/hip_runtime.h>

// Math (unchanged from verified kernel): softmax over a size-1 axis == 1, so
//   out = relu(x @ (gamma*W3 + W4)^T),  x:(B,20), fused M:(200,20)
// Memory floor: 210 MB out write + 21 MB x read => ~37 us @ 6.3 TB/s.
//
// R3 theory: previous mapping (thread = row-half, lanes along rows) made every
// output store a 16 B write at 800 B lane stride -> 64 cache-line touches per
// wave-store (4x minimum) -> store-request-bound (~110 us kernel, hidden just
// under the 124 us harness fills in the rocprof top-5).
//
// New mapping: lanes run along COLUMNS.
//   thread -> (cf4 = t%50, grp = t/50): a 4-column strip x 32 rows.
//   - M columns fused into 80 VGPRs ONCE per thread (amortized over 32 rows);
//     no per-row LDS traffic at all.
//   - x row read per iteration: all 50 lanes of a group read the SAME address
//     (wave-broadcast, L1-served), depth-1 prefetched.
//   - store: 50 lanes write one contiguous 800 B row segment -> ~100% line
//     efficiency (was ~25%).

#define BATCH          262144
#define DICT           20
#define COLS           200            // NUM_HEADS * DICT
#define NTHREADS       256
#define NGROUPS        4              // row groups per block; threads 200..255 idle
#define ACTIVE         (50 * NGROUPS) // 200 active threads
#define ROWS_PER_BLOCK 128
#define ROWS_PER_GROUP (ROWS_PER_BLOCK / NGROUPS)   // 32
#define NBLOCKS        (BATCH / ROWS_PER_BLOCK)     // 2048 blocks

__global__ __launch_bounds__(NTHREADS)
void attn_coalesced_kernel(const float* __restrict__ x,
                           const float* __restrict__ W3,
                           const float* __restrict__ W4,
                           const float* __restrict__ gamma,
                           float* __restrict__ out)
{
    // Fused weight matrix staged once: M[col][k], 200x20 fp32 = 16 KB,
    // 5 float4 per column. Coalesced global reads, conflict-free LDS writes.
    __shared__ float4 ldsM[COLS * 5];

    const int t = threadIdx.x;
    const float g = gamma[0];

    const float4* w3 = (const float4*)W3;
    const float4* w4 = (const float4*)W4;
    for (int i = t; i < COLS * 5; i += NTHREADS) {   // 1000 float4, 4 iters
        float4 a = w3[i], b = w4[i], m;
        m.x = fmaf(g, a.x, b.x);
        m.y = fmaf(g, a.y, b.y);
        m.z = fmaf(g, a.z, b.z);
        m.w = fmaf(g, a.w, b.w);
        ldsM[i] = m;
    }
    __syncthreads();

    if (t >= ACTIVE) return;          // after the only barrier -> legal

    const int cf4 = t % 50;           // float4-column index in [0,50)
    const int grp = t / 50;           // row group in [0,4)

    // This thread's 4 output columns of M, held in 80 VGPRs for all 32 rows.
    // One-time LDS read (20 x ds_read_b128); conflicts here are a one-off
    // prologue cost, not per-row.
    float4 m[4][5];
    {
        const float4* mp = &ldsM[cf4 * 20];
#pragma unroll
        for (int c = 0; c < 4; ++c)
#pragma unroll
            for (int k = 0; k < 5; ++k)
                m[c][k] = mp[c * 5 + k];
    }

    const int row0 = blockIdx.x * ROWS_PER_BLOCK + grp * ROWS_PER_GROUP;
    const float4* xr = (const float4*)(x + (size_t)row0 * DICT);  // 5 f4 / row
    float4* op = (float4*)(out + (size_t)row0 * COLS) + cf4;      // stride 50/row

    // depth-1 prefetch of the broadcast x row
    float4 xv[5];
#pragma unroll
    for (int k = 0; k < 5; ++k) xv[k] = xr[k];

    for (int r = 0; r < ROWS_PER_GROUP; ++r) {
        float4 xn[5];
        if (r + 1 < ROWS_PER_GROUP) {
            const float4* xq = xr + (r + 1) * 5;
#pragma unroll
            for (int k = 0; k < 5; ++k) xn[k] = xq[k];
        }

        float4 acc;
        float* ap = (float*)&acc;
#pragma unroll
        for (int c = 0; c < 4; ++c) {
            // dot(M[4*cf4+c][:], x[row][:]) with two partial chains for ILP
            float p0 = 0.f, p1 = 0.f;
#pragma unroll
            for (int k = 0; k < 5; ++k) {
                p0 = fmaf(m[c][k].x, xv[k].x, p0);
                p1 = fmaf(m[c][k].y, xv[k].y, p1);
                p0 = fmaf(m[c][k].z, xv[k].z, p0);
                p1 = fmaf(m[c][k].w, xv[k].w, p1);
            }
            ap[c] = fmaxf(p0 + p1, 0.f);             // ReLU
        }

        // 50 consecutive lanes -> one contiguous 800 B segment. Coalesced.
        op[r * 50] = acc;

#pragma unroll
        for (int k = 0; k < 5; ++k) xv[k] = xn[k];
    }
}

extern "C" void kernel_launch(void* const* d_in, const int* in_sizes, int n_in,
                              void* d_out, int out_size, void* d_ws, size_t ws_size,
                              hipStream_t stream) {
    const float* x     = (const float*)d_in[0];
    // d_in[1] = W1, d_in[2] = W2 : mathematically unused (softmax over size-1 axis)
    const float* W3    = (const float*)d_in[3];
    const float* W4    = (const float*)d_in[4];
    const float* gamma = (const float*)d_in[5];
    float* out = (float*)d_out;

    attn_coalesced_kernel<<<NBLOCKS, NTHREADS, 0, stream>>>(x, W3, W4, gamma, out);
}

// Round 2
// 261.200 us; speedup vs baseline: 1.2817x; 1.2817x over previous
//
#include <hip/hip_runtime.h>

// Math (verified): softmax over a size-1 axis == 1, so
//   out = relu(x @ (gamma*W3 + W4)^T),  x:(B,20), fused M:(200,20)
// Memory floor: 210 MB out write + 21 MB x read => ~37 us @ 6.3 TB/s.
//
// R3 result: column-lane mapping fixed the stores (WRITE_SIZE = exact 210 MB)
// but the per-row GLOBAL broadcast x load became a ~400-cycle latency chain
// (VALUBusy 21%, HBM 17%, occ 10.5% -> latency-bound at 161 us).
//
// R4: x tile (128 rows x 20 f32 = 10 KB) is cooperatively staged into LDS
// once per block (coalesced), so the main loop touches global memory ONLY
// with fire-and-forget stores. Per-row x comes from LDS broadcast reads
// (~120 cy latency, depth-1 prefetched, 2-way bank aliasing = free).
//   thread -> (cf4 = t%50, grp = t/50): 4-col strip x 32 rows.
//   - M columns fused in 80 VGPRs (one-off LDS read; its ~16-way conflict
//     is prologue-only, ~0.4 us/CU -- measured 1.5M cycles, left as is)
//   - store: 50 lanes -> contiguous 800 B row segment (kept from R3).

#define BATCH          262144
#define DICT           20
#define COLS           200            // NUM_HEADS * DICT
#define NTHREADS       256
#define NGROUPS        4              // row groups per block; threads 200..255 idle
#define ACTIVE         (50 * NGROUPS) // 200 active threads
#define ROWS_PER_BLOCK 128
#define ROWS_PER_GROUP (ROWS_PER_BLOCK / NGROUPS)   // 32
#define NBLOCKS        (BATCH / ROWS_PER_BLOCK)     // 2048 blocks

__global__ __launch_bounds__(NTHREADS)
void attn_ldsx_kernel(const float* __restrict__ x,
                      const float* __restrict__ W3,
                      const float* __restrict__ W4,
                      const float* __restrict__ gamma,
                      float* __restrict__ out)
{
    __shared__ float4 ldsM[COLS * 5];            // 16 KB fused weights
    __shared__ float4 ldsX[ROWS_PER_BLOCK * 5];  // 10 KB x tile

    const int t = threadIdx.x;
    const float g = gamma[0];

    // Stage fused M = g*W3 + W4 (coalesced reads, conflict-free writes).
    const float4* w3 = (const float4*)W3;
    const float4* w4 = (const float4*)W4;
    for (int i = t; i < COLS * 5; i += NTHREADS) {   // 1000 f4, 4 iters
        float4 a = w3[i], b = w4[i], m;
        m.x = fmaf(g, a.x, b.x);
        m.y = fmaf(g, a.y, b.y);
        m.z = fmaf(g, a.z, b.z);
        m.w = fmaf(g, a.w, b.w);
        ldsM[i] = m;
    }
    // Stage this block's x tile (coalesced 16 B loads, conflict-free writes).
    const float4* xg = (const float4*)(x + (size_t)blockIdx.x * ROWS_PER_BLOCK * DICT);
    for (int i = t; i < ROWS_PER_BLOCK * 5; i += NTHREADS)   // 640 f4, 3 iters
        ldsX[i] = xg[i];
    __syncthreads();

    if (t >= ACTIVE) return;          // after the only barrier -> legal

    const int cf4 = t % 50;           // float4-column index in [0,50)
    const int grp = t / 50;           // row group in [0,4)

    // This thread's 4 output columns of M, in 80 VGPRs for all 32 rows.
    float4 m[4][5];
    {
        const float4* mp = &ldsM[cf4 * 20];
#pragma unroll
        for (int c = 0; c < 4; ++c)
#pragma unroll
            for (int k = 0; k < 5; ++k)
                m[c][k] = mp[c * 5 + k];
    }

    const int row0 = blockIdx.x * ROWS_PER_BLOCK + grp * ROWS_PER_GROUP;
    float4* op = (float4*)(out + (size_t)row0 * COLS) + cf4;   // stride 50 f4/row
    const float4* xl = &ldsX[grp * ROWS_PER_GROUP * 5];

    // depth-1 prefetch of the broadcast x row (LDS, ~120 cy)
    float4 xv[5];
#pragma unroll
    for (int k = 0; k < 5; ++k) xv[k] = xl[k];

    for (int r = 0; r < ROWS_PER_GROUP; ++r) {
        float4 xn[5];
        if (r + 1 < ROWS_PER_GROUP) {
            const float4* xq = xl + (r + 1) * 5;
#pragma unroll
            for (int k = 0; k < 5; ++k) xn[k] = xq[k];
        }

        float4 acc;
        float* ap = (float*)&acc;
#pragma unroll
        for (int c = 0; c < 4; ++c) {
            // dot(M[4*cf4+c][:], x[row][:]) with two partial chains for ILP
            float p0 = 0.f, p1 = 0.f;
#pragma unroll
            for (int k = 0; k < 5; ++k) {
                p0 = fmaf(m[c][k].x, xv[k].x, p0);
                p1 = fmaf(m[c][k].y, xv[k].y, p1);
                p0 = fmaf(m[c][k].z, xv[k].z, p0);
                p1 = fmaf(m[c][k].w, xv[k].w, p1);
            }
            ap[c] = fmaxf(p0 + p1, 0.f);             // ReLU
        }

        // 50 consecutive lanes -> one contiguous 800 B segment. Coalesced.
        op[r * 50] = acc;

#pragma unroll
        for (int k = 0; k < 5; ++k) xv[k] = xn[k];
    }
}

extern "C" void kernel_launch(void* const* d_in, const int* in_sizes, int n_in,
                              void* d_out, int out_size, void* d_ws, size_t ws_size,
                              hipStream_t stream) {
    const float* x     = (const float*)d_in[0];
    // d_in[1] = W1, d_in[2] = W2 : mathematically unused (softmax over size-1 axis)
    const float* W3    = (const float*)d_in[3];
    const float* W4    = (const float*)d_in[4];
    const float* gamma = (const float*)d_in[5];
    float* out = (float*)d_out;

    attn_ldsx_kernel<<<NBLOCKS, NTHREADS, 0, stream>>>(x, W3, W4, gamma, out);
}

// Round 3
// 253.522 us; speedup vs baseline: 1.3205x; 1.0303x over previous
//
#include <hip/hip_runtime.h>

// Math (verified): softmax over a size-1 axis == 1, so
//   out = relu(x @ (gamma*W3 + W4)^T),  x:(B,20), fused M:(200,20)
// Memory floor: 210 MB out write + 21 MB x read => ~37 us @ 6.3 TB/s.
//
// Ladder so far: R0 row-lane stores (uncoalesced) ~116 us -> R1 col-lane +
// global broadcast x (latency chain) 161 us -> R2 col-lane + LDS x ~87 us
// (= dur 261 - 174 us fixed harness overhead).
//
// R5 attacks the remaining ~54 us over the store floor on three fronts:
//  1. occupancy: thread = 2 columns (m[2][5] = 40 VGPR, was 80) ->
//     ~100 VGPR total, __launch_bounds__(256,4): 4 waves/SIMD (was 3).
//  2. store throttling: unroll 2 -> two independent acc sets -> 2
//     outstanding stores per wave instead of 1 (vmcnt slack).
//  3. prologue: M read DIRECTLY from global (16 KB, L2-resident) into regs;
//     deletes ldsM staging + the 1.5M-cycle 16-way-conflicted LDS read.
// Stores stay coalesced: 100 lanes x float2 = contiguous 800 B per row-group.

#define BATCH          262144
#define DICT           20
#define COLS           200                      // NUM_HEADS * DICT
#define NTHREADS       256
#define CPT            100                      // float2 column strips per row
#define NGROUPS        2
#define ACTIVE         (CPT * NGROUPS)          // 200 active threads
#define ROWS_PER_BLOCK 128
#define ROWS_PER_GROUP (ROWS_PER_BLOCK / NGROUPS)   // 64
#define NBLOCKS        (BATCH / ROWS_PER_BLOCK)     // 2048

__global__ __launch_bounds__(NTHREADS, 4)
void attn_v5_kernel(const float* __restrict__ x,
                    const float* __restrict__ W3,
                    const float* __restrict__ W4,
                    const float* __restrict__ gamma,
                    float* __restrict__ out)
{
    __shared__ float4 ldsX[ROWS_PER_BLOCK * 5];   // 10 KB x tile

    const int t = threadIdx.x;

    // Stage this block's x tile (coalesced 16 B loads, conflict-free writes).
    const float4* xg = (const float4*)(x + (size_t)blockIdx.x * ROWS_PER_BLOCK * DICT);
    for (int i = t; i < ROWS_PER_BLOCK * 5; i += NTHREADS)   // 640 f4, 3 iters
        ldsX[i] = xg[i];
    __syncthreads();

    if (t >= ACTIVE) return;          // after the only barrier -> legal

    const float g   = gamma[0];
    const int   c2  = t % CPT;        // float2-column index in [0,100)
    const int   grp = t / CPT;        // row group in [0,2)

    // Fused M = g*W3 + W4 for this thread's 2 columns, straight from global.
    // W3/W4 are 16 KB each -> L1/L2-resident after the first blocks touch
    // them. 40 VGPRs, amortized over 64 rows. No LDS, no bank conflicts.
    float4 m0[5], m1[5];
    {
        const float4* a0 = (const float4*)(W3 + (2 * c2 + 0) * DICT);
        const float4* b0 = (const float4*)(W4 + (2 * c2 + 0) * DICT);
        const float4* a1 = (const float4*)(W3 + (2 * c2 + 1) * DICT);
        const float4* b1 = (const float4*)(W4 + (2 * c2 + 1) * DICT);
#pragma unroll
        for (int k = 0; k < 5; ++k) {
            float4 p = a0[k], q = b0[k], r;
            r.x = fmaf(g, p.x, q.x); r.y = fmaf(g, p.y, q.y);
            r.z = fmaf(g, p.z, q.z); r.w = fmaf(g, p.w, q.w);
            m0[k] = r;
            float4 s = a1[k], u = b1[k], v;
            v.x = fmaf(g, s.x, u.x); v.y = fmaf(g, s.y, u.y);
            v.z = fmaf(g, s.z, u.z); v.w = fmaf(g, s.w, u.w);
            m1[k] = v;
        }
    }

    const int row0 = blockIdx.x * ROWS_PER_BLOCK + grp * ROWS_PER_GROUP;
    const float4* xl = &ldsX[grp * ROWS_PER_GROUP * 5];
    float* ob = out + (size_t)row0 * COLS + 2 * c2;

    // 64 rows. x row read is wave-broadcast LDS (addr depends only on grp/r).
    // unroll 2: batched ds_reads + two independent stores in flight.
#pragma unroll 2
    for (int r = 0; r < ROWS_PER_GROUP; ++r) {
        float4 xv[5];
#pragma unroll
        for (int k = 0; k < 5; ++k) xv[k] = xl[r * 5 + k];

        // dot(M[2c2][:], x) and dot(M[2c2+1][:], x), two chains each for ILP
        float p0 = 0.f, p1 = 0.f, q0 = 0.f, q1 = 0.f;
#pragma unroll
        for (int k = 0; k < 5; ++k) {
            p0 = fmaf(m0[k].x, xv[k].x, p0);
            p1 = fmaf(m0[k].y, xv[k].y, p1);
            p0 = fmaf(m0[k].z, xv[k].z, p0);
            p1 = fmaf(m0[k].w, xv[k].w, p1);
            q0 = fmaf(m1[k].x, xv[k].x, q0);
            q1 = fmaf(m1[k].y, xv[k].y, q1);
            q0 = fmaf(m1[k].z, xv[k].z, q0);
            q1 = fmaf(m1[k].w, xv[k].w, q1);
        }
        float2 o;
        o.x = fmaxf(p0 + p1, 0.f);               // ReLU
        o.y = fmaxf(q0 + q1, 0.f);

        // 100 consecutive lanes -> one contiguous 800 B row segment.
        *(float2*)(ob + (size_t)r * COLS) = o;
    }
}

extern "C" void kernel_launch(void* const* d_in, const int* in_sizes, int n_in,
                              void* d_out, int out_size, void* d_ws, size_t ws_size,
                              hipStream_t stream) {
    const float* x     = (const float*)d_in[0];
    // d_in[1] = W1, d_in[2] = W2 : mathematically unused (softmax over size-1 axis)
    const float* W3    = (const float*)d_in[3];
    const float* W4    = (const float*)d_in[4];
    const float* gamma = (const float*)d_in[5];
    float* out = (float*)d_out;

    attn_v5_kernel<<<NBLOCKS, NTHREADS, 0, stream>>>(x, W3, W4, gamma, out);
}

// Round 5
// 248.345 us; speedup vs baseline: 1.3481x; 1.0208x over previous
//
#include <hip/hip_runtime.h>

// Math (verified): softmax over a size-1 axis == 1, so
//   out = relu(x @ (gamma*W3 + W4)^T),  x:(B,20), fused M:(200,20)
// Memory floor: 210 MB out write + 21 MB x read => ~34-37 us.
//
// Ladder: R0 row-lane stores ~116 -> R1 global-broadcast x (latency) 161 ->
// R2 LDS-x float4/50-lane ~87 -> R3(v5) float2/100-lane + M-from-global ~79
// (dur - 174 us fixed harness overhead). R4: compile fix only (nontemporal
// builtins need native vector types, not HIP_vector_type).
//
// v6 theory: v5's mapping doubled per-row ds_read and store instruction
// rates (each row broadcast-read by 2 waves, 40 FMA/row/wave) and dropped
// R2's explicit prefetch, so LDS latency + store drain intrude on every
// FMA burst. v6 = wave-aligned float4 mapping (1 wave per row, 5 ds_reads
// per 80 wave-FMAs, one 800 B full-row store) + explicit depth-1 pipeline
// (next row's ds_reads issued before current row's FMAs) + manual unroll 2
// (distinct accs -> ~4 outstanding stores) + M-from-global kept from v5.

#define BATCH          262144
#define DICT           20
#define COLS           200                        // NUM_HEADS * DICT
#define NTHREADS       256                        // 4 waves
#define ROWS_PER_BLOCK 128
#define ROWS_PER_WAVE  32
#define NBLOCKS        (BATCH / ROWS_PER_BLOCK)   // 2048

typedef float f32x4 __attribute__((ext_vector_type(4)));  // native type for
                                                          // nontemporal builtins

__global__ __launch_bounds__(NTHREADS, 3)
void attn_v6_kernel(const float* __restrict__ x,
                    const float* __restrict__ W3,
                    const float* __restrict__ W4,
                    const float* __restrict__ gamma,
                    float* __restrict__ out)
{
    __shared__ f32x4 ldsX[ROWS_PER_BLOCK * 5];   // 10 KB x tile

    const int t = threadIdx.x;

    // Stage x tile: coalesced nontemporal 16 B loads (x is read once chip-wide).
    const f32x4* xg = (const f32x4*)(x + (size_t)blockIdx.x * ROWS_PER_BLOCK * DICT);
    for (int i = t; i < ROWS_PER_BLOCK * 5; i += NTHREADS)
        ldsX[i] = __builtin_nontemporal_load(&xg[i]);
    __syncthreads();

    const int lane = t & 63;
    const int wv   = t >> 6;          // wave = row group (wave-uniform rows)
    if (lane >= 50) return;           // after the only barrier -> legal

    const float g   = gamma[0];
    const int   cf4 = lane;           // float4-column strip in [0,50)

    // Fused M = g*W3 + W4 for this thread's 4 columns, straight from global
    // (16 KB, L2-resident). 80 VGPRs, amortized over 32 rows. No LDS use.
    f32x4 m[4][5];
#pragma unroll
    for (int c = 0; c < 4; ++c) {
        const f32x4* a = (const f32x4*)(W3 + (4 * cf4 + c) * DICT);
        const f32x4* b = (const f32x4*)(W4 + (4 * cf4 + c) * DICT);
#pragma unroll
        for (int k = 0; k < 5; ++k) {
            f32x4 p = a[k], q = b[k], r;
            r.x = fmaf(g, p.x, q.x); r.y = fmaf(g, p.y, q.y);
            r.z = fmaf(g, p.z, q.z); r.w = fmaf(g, p.w, q.w);
            m[c][k] = r;
        }
    }

    const int row0 = blockIdx.x * ROWS_PER_BLOCK + wv * ROWS_PER_WAVE;
    const f32x4* xl = &ldsX[wv * ROWS_PER_WAVE * 5];   // wave-uniform base
    f32x4* op = (f32x4*)(out + (size_t)row0 * COLS) + cf4;  // 50 f4/row

#define DOT4(ACC, XV)                                          \
    {                                                          \
        float* ap_ = (float*)&(ACC);                           \
        _Pragma("unroll")                                      \
        for (int c = 0; c < 4; ++c) {                          \
            float p0 = 0.f, p1 = 0.f;                          \
            _Pragma("unroll")                                  \
            for (int k = 0; k < 5; ++k) {                      \
                p0 = fmaf(m[c][k].x, (XV)[k].x, p0);           \
                p1 = fmaf(m[c][k].y, (XV)[k].y, p1);           \
                p0 = fmaf(m[c][k].z, (XV)[k].z, p0);           \
                p1 = fmaf(m[c][k].w, (XV)[k].w, p1);           \
            }                                                  \
            ap_[c] = fmaxf(p0 + p1, 0.f);                      \
        }                                                      \
    }

    // Depth-1 software pipeline: next row's broadcast ds_reads are issued
    // BEFORE current row's 80-FMA block, so ~120 cy LDS latency hides under
    // ~160 cy of FMA issue. Manual unroll 2 -> acc0/acc1 distinct regs ->
    // stores reuse data regs at distance 2 (vmcnt slack ~4).
    f32x4 xv[5], xn[5];
#pragma unroll
    for (int k = 0; k < 5; ++k) xv[k] = xl[k];

    for (int r = 0; r < ROWS_PER_WAVE; r += 2) {
        // prefetch row r+1
#pragma unroll
        for (int k = 0; k < 5; ++k) xn[k] = xl[(r + 1) * 5 + k];

        f32x4 acc0;
        DOT4(acc0, xv)
        __builtin_nontemporal_store(acc0, &op[(size_t)r * 50]);

        // prefetch row r+2
        if (r + 2 < ROWS_PER_WAVE) {
#pragma unroll
            for (int k = 0; k < 5; ++k) xv[k] = xl[(r + 2) * 5 + k];
        }

        f32x4 acc1;
        DOT4(acc1, xn)
        __builtin_nontemporal_store(acc1, &op[(size_t)(r + 1) * 50]);
    }
#undef DOT4
}

extern "C" void kernel_launch(void* const* d_in, const int* in_sizes, int n_in,
                              void* d_out, int out_size, void* d_ws, size_t ws_size,
                              hipStream_t stream) {
    const float* x     = (const float*)d_in[0];
    // d_in[1] = W1, d_in[2] = W2 : mathematically unused (softmax over size-1 axis)
    const float* W3    = (const float*)d_in[3];
    const float* W4    = (const float*)d_in[4];
    const float* gamma = (const float*)d_in[5];
    float* out = (float*)d_out;

    attn_v6_kernel<<<NBLOCKS, NTHREADS, 0, stream>>>(x, W3, W4, gamma, out);
}